// Round 2
// baseline (5741.081 us; speedup 1.0000x reference)
//
#include <hip/hip_runtime.h>
#include <math.h>

#define HID 256
#define TWOH 512
#define ROWS 8192   // B*S
#define NLAYER 4
#define TMAX 50
#define DT 0.05f
#define EPSC 1e-3f

typedef float f32x4 __attribute__((ext_vector_type(4)));
typedef long  long2v __attribute__((ext_vector_type(2)));
typedef unsigned char u8;

// fp8 helpers (OCP e4m3 on gfx950)
__device__ inline u8 f32_to_fp8(float v) {
    return (u8)(__builtin_amdgcn_cvt_pk_fp8_f32(v, v, 0, 0) & 0xff);
}
__device__ inline float fp8_to_f32(u8 b) {
    return __builtin_amdgcn_cvt_f32_fp8((int)b, 0);
}

// ---------------------------------------------------------------------------
// Pair-packed fragment-major fp8 weights. Per wave-column-group wv
// (d-range [wv*32, wv*32+32)), fragment-PAIR (L,wv,ci,g) is 1024 B:
// lane's 16 B at lane*16 = { h=0 fragment 8 B | h=1 fragment 8 B } so the
// K-loop loads one dwordx4 per (ci,g) instead of two dwordx2.
//   g=0 -> tau columns, g=1 -> forcing columns; col d = wv*32 + h*16 + l15
//   k = ci*32 + quad*8 + j
// e bits: j:0-2, h:3, lane:4-9, g:10, ci:11-14, wv:15-17, L:18-19.
// tau row d: Wt[d][k]; forcing row d: k<256 ? Wi[d][k] : Ws[d][k-256].
// ---------------------------------------------------------------------------
__global__ void pack_w_kernel(const float* __restrict__ Ws,
                              const float* __restrict__ Wi,
                              const float* __restrict__ Wt,
                              u8* __restrict__ Wf) {
    int e = blockIdx.x * 256 + threadIdx.x;     // [0, 2^20)
    int j    = e & 7;
    int h    = (e >> 3) & 1;
    int lane = (e >> 4) & 63;
    int g    = (e >> 10) & 1;
    int ci   = (e >> 11) & 15;
    int wv   = (e >> 15) & 7;
    int L    = (e >> 18);
    int l15  = lane & 15;
    int quad = lane >> 4;
    int d = wv * 32 + h * 16 + l15;
    int k = ci * 32 + quad * 8 + j;
    float v;
    if (g == 0) {
        v = Wt[(size_t)L * HID * TWOH + (size_t)d * TWOH + k];
    } else {
        v = (k < HID) ? Wi[(size_t)L * HID * HID + (size_t)d * HID + k]
                      : Ws[(size_t)L * HID * HID + (size_t)d * HID + (k - HID)];
    }
    Wf[e] = f32_to_fp8(v);
}

__global__ void pack_b_kernel(const float* __restrict__ bs,
                              const float* __restrict__ bi,
                              const float* __restrict__ bt,
                              float* __restrict__ bp) {
    int idx = blockIdx.x * 256 + threadIdx.x;   // [0, 4*512): L*512 + n
    int L = idx / TWOH;
    int n = idx % TWOH;
    int d = n >> 1;
    bp[idx] = ((n & 1) == 0) ? bt[L * HID + d]
                             : (bs[L * HID + d] + bi[L * HID + d]);
}

// ---------------------------------------------------------------------------
// Persistent kernel: 256 blocks x 1024 threads (16 waves = 2 row-groups x
// 8 col-groups), block owns rows [32b, 32b+32). h state double-buffered in
// LDS (fp8, swizzled) -> ONE barrier per (t,L) stage. h also lives packed
// in registers for the epilogue (no LDS byte reads); biases in registers.
// Weights stream L2 -> registers as 1 KB pair-fragments, depth-4 prefetch;
// the two row-group waves of a col-group read the same stream (L1 reuse).
// ---------------------------------------------------------------------------
__global__ __launch_bounds__(1024, 4) void persistent_kernel(
    const float* __restrict__ x,
    const u8* __restrict__ Wf,
    const float* __restrict__ bp,
    float* __restrict__ deltas,
    float* __restrict__ out)
{
    __shared__ u8 sX[32 * 256];                 //  8 KB
    __shared__ u8 sH[2][NLAYER][32 * 256];      // 64 KB (double-buffered)
    __shared__ float sRed[16];

    const int tid  = threadIdx.x;
    const int lane = tid & 63;
    const int w    = tid >> 6;               // 0..15
    const int wv   = w & 7;                  // col group (d-base wv*32)
    const int mg   = w >> 3;                 // row group (rows mg*16..+16)
    const int l15  = lane & 15;
    const int quad = lane >> 4;              // 0..3
    const int w32  = wv * 32;
    const size_t rowbase = (size_t)blockIdx.x * 32;

    // ---- stage x -> sX (fp8, swizzled): 32 rows x 32 segs = 1024 units ----
    {
        int r = tid >> 5, seg = tid & 31;
        const float* gx = x + (rowbase + r) * HID + seg * 8;
        float4 v0 = *(const float4*)gx;
        float4 v1 = *(const float4*)(gx + 4);
        int lo = __builtin_amdgcn_cvt_pk_fp8_f32(v0.x, v0.y, 0, 0);
        lo     = __builtin_amdgcn_cvt_pk_fp8_f32(v0.z, v0.w, lo, 1);
        int hi = __builtin_amdgcn_cvt_pk_fp8_f32(v1.x, v1.y, 0, 0);
        hi     = __builtin_amdgcn_cvt_pk_fp8_f32(v1.z, v1.w, hi, 1);
        long pk = ((long)(unsigned int)lo) | ((long)hi << 32);
        *(long*)&sX[r * 256 + (seg ^ r) * 8] = pk;
    }
    // ---- zero both h buffers: 64 KB = 8192 longs ----
    {
        long* hflat = (long*)&sH[0][0][0];
        #pragma unroll
        for (int it = 0; it < 8; ++it) hflat[tid + it * 1024] = 0;
    }
    // ---- biases -> registers: (b_tau, b_forcing) for this lane's d's ----
    float2 btf[NLAYER][2];
    #pragma unroll
    for (int L = 0; L < NLAYER; ++L) {
        #pragma unroll
        for (int ntp = 0; ntp < 2; ++ntp) {
            int d = w32 + ntp * 16 + l15;
            btf[L][ntp] = *(const float2*)(bp + L * TWOH + 2 * d);
        }
    }
    // ---- packed fp8 h state for this lane's 8 outputs per layer ----
    int hpk[NLAYER][2] = {};   // [L][ntp], byte r = row mg*16+quad*4+r

    __syncthreads();

    #pragma unroll 1
    for (int t = 0; t < TMAX; ++t) {
        const int rs = t & 1, ws = rs ^ 1;
        float dmax = 0.0f;
        #pragma unroll
        for (int L = 0; L < NLAYER; ++L) {
            const u8* Alo = (L == 0) ? sX : &sH[ws][L - 1][0];  // cur_in (k<256)
            const u8* Ahi = &sH[rs][L][0];                      // h_prev (k>=256)
            u8*       Hout = &sH[ws][L][0];
            // wave's pair-fragment stream: 32 KB contiguous per (L, wv)
            const u8* wb = Wf + ((size_t)(L * 8 + wv) << 15) + (size_t)lane * 16;

            f32x4 acc[4];   // 0: tau ntp0, 1: tau ntp1, 2: forc ntp0, 3: forc ntp1
            #pragma unroll
            for (int n = 0; n < 4; ++n) acc[n] = (f32x4){0.f, 0.f, 0.f, 0.f};

            // depth-4 register prefetch of B pair-fragments (1 KB each)
            long2v bb[4][2];
            #pragma unroll
            for (int pi = 0; pi < 4; ++pi)
                #pragma unroll
                for (int g = 0; g < 2; ++g)
                    bb[pi][g] = *(const long2v*)(wb + (size_t)((pi * 2 + g) << 10));

            const int row = mg * 16 + l15;
            #pragma unroll
            for (int ci = 0; ci < 16; ++ci) {            // k = 32*ci
                const int p = ci & 3;
                const u8* Asrc = (ci < 8) ? Alo : Ahi;   // static under unroll
                const int seg = (ci & 7) * 4 + quad;     // 8-B seg in [0,32)
                long a = *(const long*)&Asrc[row * 256 + (seg ^ row) * 8];
                acc[0] = __builtin_amdgcn_mfma_f32_16x16x32_fp8_fp8(a, bb[p][0][0], acc[0], 0, 0, 0);
                acc[1] = __builtin_amdgcn_mfma_f32_16x16x32_fp8_fp8(a, bb[p][0][1], acc[1], 0, 0, 0);
                acc[2] = __builtin_amdgcn_mfma_f32_16x16x32_fp8_fp8(a, bb[p][1][0], acc[2], 0, 0, 0);
                acc[3] = __builtin_amdgcn_mfma_f32_16x16x32_fp8_fp8(a, bb[p][1][1], acc[3], 0, 0, 0);
                if (ci + 4 < 16) {
                    #pragma unroll
                    for (int g = 0; g < 2; ++g)
                        bb[p][g] = *(const long2v*)(wb + (size_t)(((ci + 4) * 2 + g) << 10));
                }
            }

            // Epilogue. C/D: col = l15 (tile ntp), row = mg*16 + quad*4 + r.
            // h_prev from registers (bit-identical to the LDS fp8 bytes).
            #pragma unroll
            for (int ntp = 0; ntp < 2; ++ntp) {
                const int d = w32 + ntp * 16 + l15;
                const float2 b2 = btf[L][ntp];
                const int seg = d >> 3, dlow = d & 7;
                const int hold = hpk[L][ntp];
                int hnew = 0;
                #pragma unroll
                for (int r = 0; r < 4; ++r) {
                    float tpre = acc[ntp][r]     + b2.x;
                    float fpre = acc[ntp + 2][r] + b2.y;
                    tpre = fminf(30.f, fmaxf(-30.f, tpre));
                    fpre = fminf(15.f, fmaxf(-15.f, fpre));
                    // h/(sigma(t)+1e-6) == h*(1+u)/(1+eps+eps*u), u=e^-t
                    float u   = __expf(-tpre);
                    float den = 1.0f + 1e-6f + 1e-6f * u;
                    float rcp = __builtin_amdgcn_rcpf(den);
                    float e2  = __expf(2.0f * fpre);
                    float r2  = __builtin_amdgcn_rcpf(e2 + 1.0f);
                    float fo  = (e2 - 1.0f) * r2;
                    float h   = fp8_to_f32((u8)(hold >> (8 * r)));
                    float gq  = h * (1.0f + u) * rcp;
                    float nv  = h + DT * (fo - gq);
                    nv = fminf(10.0f, fmaxf(-10.0f, nv));
                    u8 byte = f32_to_fp8(nv);
                    hnew |= ((int)byte) << (8 * r);
                    const int orow = mg * 16 + quad * 4 + r;
                    Hout[orow * 256 + (seg ^ orow) * 8 + dlow] = byte;
                    dmax = fmaxf(dmax, fabsf(nv - h));
                }
                hpk[L][ntp] = hnew;
            }
            if (L == NLAYER - 1) {
                #pragma unroll
                for (int off = 32; off > 0; off >>= 1)
                    dmax = fmaxf(dmax, __shfl_xor(dmax, off));
                if (lane == 0) sRed[w] = dmax;
            }
            __syncthreads();   // ws[L] (and sRed) visible; only barrier/stage
        } // L

        if (tid == 0) {
            float m = sRed[0];
            #pragma unroll
            for (int i = 1; i < 16; ++i) m = fmaxf(m, sRed[i]);
            atomicMax((unsigned int*)(deltas + t), __float_as_uint(m));
        }
    } // t

    // ---- final output: layer-3 states from write-side of t=TMAX-1 ----
    {
        const u8* fin = &sH[((TMAX - 1) & 1) ^ 1][NLAYER - 1][0];
        int r = tid >> 5, seg = tid & 31;
        long v = *(const long*)&fin[r * 256 + (seg ^ r) * 8];
        int lo = (int)(v & 0xffffffffl);
        int hi = (int)(v >> 32);
        float* go = out + (rowbase + r) * HID + seg * 8;
        float4 o0, o1;
        o0.x = __builtin_amdgcn_cvt_f32_fp8(lo, 0);
        o0.y = __builtin_amdgcn_cvt_f32_fp8(lo, 1);
        o0.z = __builtin_amdgcn_cvt_f32_fp8(lo, 2);
        o0.w = __builtin_amdgcn_cvt_f32_fp8(lo, 3);
        o1.x = __builtin_amdgcn_cvt_f32_fp8(hi, 0);
        o1.y = __builtin_amdgcn_cvt_f32_fp8(hi, 1);
        o1.z = __builtin_amdgcn_cvt_f32_fp8(hi, 2);
        o1.w = __builtin_amdgcn_cvt_f32_fp8(hi, 3);
        *(float4*)go = o0;
        *(float4*)(go + 4) = o1;
    }
}

__global__ void result_kernel(const float* __restrict__ deltas,
                              float* __restrict__ out) {
    if (threadIdx.x == 0) {
        int res = TMAX;
        for (int t = 0; t < TMAX; ++t) {
            if (deltas[t] < EPSC) { res = t; break; }
        }
        out[(size_t)ROWS * HID] = (float)res;
    }
}

// ---------------------------------------------------------------------------
extern "C" void kernel_launch(void* const* d_in, const int* in_sizes, int n_in,
                              void* d_out, int out_size, void* d_ws, size_t ws_size,
                              hipStream_t stream) {
    const float* x  = (const float*)d_in[0];
    const float* Ws = (const float*)d_in[1];
    const float* bs = (const float*)d_in[2];
    const float* Wi = (const float*)d_in[3];
    const float* bi = (const float*)d_in[4];
    const float* Wt = (const float*)d_in[5];
    const float* bt = (const float*)d_in[6];
    float* out = (float*)d_out;

    char* p = (char*)d_ws;
    u8*    Wf     = (u8*)p;    p += (size_t)NLAYER * TWOH * TWOH;            // 1 MB
    float* bp     = (float*)p; p += (size_t)NLAYER * TWOH * sizeof(float);   // 8 KB
    float* deltas = (float*)p; p += 64 * sizeof(float);

    hipMemsetAsync(deltas, 0, 64 * sizeof(float), stream);
    pack_w_kernel<<<(NLAYER * TWOH * TWOH) / 256, 256, 0, stream>>>(Ws, Wi, Wt, Wf);
    pack_b_kernel<<<(NLAYER * TWOH) / 256, 256, 0, stream>>>(bs, bi, bt, bp);

    persistent_kernel<<<256, 1024, 0, stream>>>(x, Wf, bp, deltas, out);
    result_kernel<<<1, 64, 0, stream>>>(deltas, out);
}

// Round 3
// 5595.243 us; speedup vs baseline: 1.0261x; 1.0261x over previous
//
#include <hip/hip_runtime.h>
#include <math.h>

#define HID 256
#define TWOH 512
#define ROWS 8192   // B*S
#define NLAYER 4
#define TMAX 50
#define DT 0.05f
#define EPSC 1e-3f

typedef float f32x4 __attribute__((ext_vector_type(4)));
typedef long  long2v __attribute__((ext_vector_type(2)));
typedef unsigned char u8;

// fp8 helpers (OCP e4m3 on gfx950)
__device__ inline u8 f32_to_fp8(float v) {
    return (u8)(__builtin_amdgcn_cvt_pk_fp8_f32(v, v, 0, 0) & 0xff);
}
__device__ inline float fp8_to_f32(u8 b) {
    return __builtin_amdgcn_cvt_f32_fp8((int)b, 0);
}

// ---------------------------------------------------------------------------
// Pair-packed fragment-major fp8 weights. Per wave-column-group wv
// (d-range [wv*32, wv*32+32)), fragment-PAIR (L,wv,ci,g) is 1024 B:
// lane's 16 B at lane*16 = { h=0 fragment 8 B | h=1 fragment 8 B } so the
// K-loop loads one dwordx4 per (ci,g) instead of two dwordx2.
//   g=0 -> tau columns, g=1 -> forcing columns; col d = wv*32 + h*16 + l15
//   k = ci*32 + quad*8 + j
// e bits: j:0-2, h:3, lane:4-9, g:10, ci:11-14, wv:15-17, L:18-19.
// tau row d: Wt[d][k]; forcing row d: k<256 ? Wi[d][k] : Ws[d][k-256].
// ---------------------------------------------------------------------------
__global__ void pack_w_kernel(const float* __restrict__ Ws,
                              const float* __restrict__ Wi,
                              const float* __restrict__ Wt,
                              u8* __restrict__ Wf) {
    int e = blockIdx.x * 256 + threadIdx.x;     // [0, 2^20)
    int j    = e & 7;
    int h    = (e >> 3) & 1;
    int lane = (e >> 4) & 63;
    int g    = (e >> 10) & 1;
    int ci   = (e >> 11) & 15;
    int wv   = (e >> 15) & 7;
    int L    = (e >> 18);
    int l15  = lane & 15;
    int quad = lane >> 4;
    int d = wv * 32 + h * 16 + l15;
    int k = ci * 32 + quad * 8 + j;
    float v;
    if (g == 0) {
        v = Wt[(size_t)L * HID * TWOH + (size_t)d * TWOH + k];
    } else {
        v = (k < HID) ? Wi[(size_t)L * HID * HID + (size_t)d * HID + k]
                      : Ws[(size_t)L * HID * HID + (size_t)d * HID + (k - HID)];
    }
    Wf[e] = f32_to_fp8(v);
}

__global__ void pack_b_kernel(const float* __restrict__ bs,
                              const float* __restrict__ bi,
                              const float* __restrict__ bt,
                              float* __restrict__ bp) {
    int idx = blockIdx.x * 256 + threadIdx.x;   // [0, 4*512): L*512 + n
    int L = idx / TWOH;
    int n = idx % TWOH;
    int d = n >> 1;
    bp[idx] = ((n & 1) == 0) ? bt[L * HID + d]
                             : (bs[L * HID + d] + bi[L * HID + d]);
}

// ---------------------------------------------------------------------------
// Persistent kernel: 256 blocks x 1024 threads (16 waves = 2 row-groups x
// 8 col-groups), block owns rows [32b, 32b+32). h state double-buffered in
// LDS (fp8, swizzled) -> ONE barrier per (t,L) stage. h packed in registers
// for the epilogue; biases in LDS (register budget: 128 VGPR/wave at
// 4 waves/SIMD -- depth-2 B-prefetch + LDS biases keep us under, no spill).
// Weights stream L2 -> registers as 1 KB pair-fragments; the two row-group
// waves of a col-group read the same stream (L1 reuse).
// ---------------------------------------------------------------------------
__global__ __launch_bounds__(1024, 4) void persistent_kernel(
    const float* __restrict__ x,
    const u8* __restrict__ Wf,
    const float* __restrict__ bp,
    float* __restrict__ deltas,
    float* __restrict__ out)
{
    __shared__ u8 sX[32 * 256];                 //  8 KB
    __shared__ u8 sH[2][NLAYER][32 * 256];      // 64 KB (double-buffered)
    __shared__ float2 sBias[NLAYER][256];       //  8 KB (b_tau, b_forcing)
    __shared__ float sRed[16];

    const int tid  = threadIdx.x;
    const int lane = tid & 63;
    const int w    = tid >> 6;               // 0..15
    const int wv   = w & 7;                  // col group (d-base wv*32)
    const int mg   = w >> 3;                 // row group (rows mg*16..+16)
    const int l15  = lane & 15;
    const int quad = lane >> 4;              // 0..3
    const int w32  = wv * 32;
    const size_t rowbase = (size_t)blockIdx.x * 32;

    // ---- stage x -> sX (fp8, swizzled): 32 rows x 32 segs = 1024 units ----
    {
        int r = tid >> 5, seg = tid & 31;
        const float* gx = x + (rowbase + r) * HID + seg * 8;
        float4 v0 = *(const float4*)gx;
        float4 v1 = *(const float4*)(gx + 4);
        int lo = __builtin_amdgcn_cvt_pk_fp8_f32(v0.x, v0.y, 0, 0);
        lo     = __builtin_amdgcn_cvt_pk_fp8_f32(v0.z, v0.w, lo, 1);
        int hi = __builtin_amdgcn_cvt_pk_fp8_f32(v1.x, v1.y, 0, 0);
        hi     = __builtin_amdgcn_cvt_pk_fp8_f32(v1.z, v1.w, hi, 1);
        long pk = ((long)(unsigned int)lo) | ((long)hi << 32);
        *(long*)&sX[r * 256 + (seg ^ r) * 8] = pk;
    }
    // ---- zero both h buffers: 64 KB = 8192 longs ----
    {
        long* hflat = (long*)&sH[0][0][0];
        #pragma unroll
        for (int it = 0; it < 8; ++it) hflat[tid + it * 1024] = 0;
    }
    // ---- bias table -> LDS: 1024 entries, one per thread ----
    sBias[tid >> 8][tid & 255] =
        *(const float2*)(bp + (tid >> 8) * TWOH + 2 * (tid & 255));

    // ---- packed fp8 h state for this lane's 8 outputs per layer ----
    int hpk[NLAYER][2] = {};   // [L][ntp], byte r = row mg*16+quad*4+r

    __syncthreads();

    #pragma unroll 1
    for (int t = 0; t < TMAX; ++t) {
        const int rs = t & 1, ws = rs ^ 1;
        float dmax = 0.0f;
        #pragma unroll
        for (int L = 0; L < NLAYER; ++L) {
            const u8* Alo = (L == 0) ? sX : &sH[ws][L - 1][0];  // cur_in (k<256)
            const u8* Ahi = &sH[rs][L][0];                      // h_prev (k>=256)
            u8*       Hout = &sH[ws][L][0];
            // wave's pair-fragment stream: 32 KB contiguous per (L, wv)
            const u8* wb = Wf + ((size_t)(L * 8 + wv) << 15) + (size_t)lane * 16;

            f32x4 acc[4];   // 0: tau ntp0, 1: tau ntp1, 2: forc ntp0, 3: forc ntp1
            #pragma unroll
            for (int n = 0; n < 4; ++n) acc[n] = (f32x4){0.f, 0.f, 0.f, 0.f};

            // depth-2 register prefetch of B pair-fragments (1 KB each)
            long2v bb[2][2];
            #pragma unroll
            for (int pi = 0; pi < 2; ++pi)
                #pragma unroll
                for (int g = 0; g < 2; ++g)
                    bb[pi][g] = *(const long2v*)(wb + (size_t)((pi * 2 + g) << 10));

            const int row = mg * 16 + l15;
            #pragma unroll
            for (int ci = 0; ci < 16; ++ci) {            // k = 32*ci
                const int p = ci & 1;
                const u8* Asrc = (ci < 8) ? Alo : Ahi;   // static under unroll
                const int seg = (ci & 7) * 4 + quad;     // 8-B seg in [0,32)
                long a = *(const long*)&Asrc[row * 256 + (seg ^ row) * 8];
                acc[0] = __builtin_amdgcn_mfma_f32_16x16x32_fp8_fp8(a, bb[p][0][0], acc[0], 0, 0, 0);
                acc[1] = __builtin_amdgcn_mfma_f32_16x16x32_fp8_fp8(a, bb[p][0][1], acc[1], 0, 0, 0);
                acc[2] = __builtin_amdgcn_mfma_f32_16x16x32_fp8_fp8(a, bb[p][1][0], acc[2], 0, 0, 0);
                acc[3] = __builtin_amdgcn_mfma_f32_16x16x32_fp8_fp8(a, bb[p][1][1], acc[3], 0, 0, 0);
                if (ci + 2 < 16) {
                    #pragma unroll
                    for (int g = 0; g < 2; ++g)
                        bb[p][g] = *(const long2v*)(wb + (size_t)(((ci + 2) * 2 + g) << 10));
                }
            }

            // Epilogue. C/D: col = l15 (tile ntp), row = mg*16 + quad*4 + r.
            // h_prev from registers (bit-identical to the LDS fp8 bytes).
            #pragma unroll
            for (int ntp = 0; ntp < 2; ++ntp) {
                const int d = w32 + ntp * 16 + l15;
                const float2 b2 = sBias[L][d];
                const int seg = d >> 3, dlow = d & 7;
                const int hold = hpk[L][ntp];
                int hnew = 0;
                #pragma unroll
                for (int r = 0; r < 4; ++r) {
                    float tpre = acc[ntp][r]     + b2.x;
                    float fpre = acc[ntp + 2][r] + b2.y;
                    tpre = fminf(30.f, fmaxf(-30.f, tpre));
                    fpre = fminf(15.f, fmaxf(-15.f, fpre));
                    // h/(sigma(t)+1e-6) == h*(1+u)/(1+eps+eps*u), u=e^-t
                    float u   = __expf(-tpre);
                    float den = 1.0f + 1e-6f + 1e-6f * u;
                    float rcp = __builtin_amdgcn_rcpf(den);
                    float e2  = __expf(2.0f * fpre);
                    float r2  = __builtin_amdgcn_rcpf(e2 + 1.0f);
                    float fo  = (e2 - 1.0f) * r2;
                    float h   = fp8_to_f32((u8)(hold >> (8 * r)));
                    float gq  = h * (1.0f + u) * rcp;
                    float nv  = h + DT * (fo - gq);
                    nv = fminf(10.0f, fmaxf(-10.0f, nv));
                    u8 byte = f32_to_fp8(nv);
                    hnew |= ((int)byte) << (8 * r);
                    const int orow = mg * 16 + quad * 4 + r;
                    Hout[orow * 256 + (seg ^ orow) * 8 + dlow] = byte;
                    dmax = fmaxf(dmax, fabsf(nv - h));
                }
                hpk[L][ntp] = hnew;
            }
            if (L == NLAYER - 1) {
                #pragma unroll
                for (int off = 32; off > 0; off >>= 1)
                    dmax = fmaxf(dmax, __shfl_xor(dmax, off));
                if (lane == 0) sRed[w] = dmax;
            }
            __syncthreads();   // ws[L] (and sRed) visible; only barrier/stage
        } // L

        if (tid == 0) {
            float m = sRed[0];
            #pragma unroll
            for (int i = 1; i < 16; ++i) m = fmaxf(m, sRed[i]);
            atomicMax((unsigned int*)(deltas + t), __float_as_uint(m));
        }
    } // t

    // ---- final output: layer-3 states from write-side of t=TMAX-1 ----
    {
        const u8* fin = &sH[((TMAX - 1) & 1) ^ 1][NLAYER - 1][0];
        int r = tid >> 5, seg = tid & 31;
        long v = *(const long*)&fin[r * 256 + (seg ^ r) * 8];
        int lo = (int)(v & 0xffffffffl);
        int hi = (int)(v >> 32);
        float* go = out + (rowbase + r) * HID + seg * 8;
        float4 o0, o1;
        o0.x = __builtin_amdgcn_cvt_f32_fp8(lo, 0);
        o0.y = __builtin_amdgcn_cvt_f32_fp8(lo, 1);
        o0.z = __builtin_amdgcn_cvt_f32_fp8(lo, 2);
        o0.w = __builtin_amdgcn_cvt_f32_fp8(lo, 3);
        o1.x = __builtin_amdgcn_cvt_f32_fp8(hi, 0);
        o1.y = __builtin_amdgcn_cvt_f32_fp8(hi, 1);
        o1.z = __builtin_amdgcn_cvt_f32_fp8(hi, 2);
        o1.w = __builtin_amdgcn_cvt_f32_fp8(hi, 3);
        *(float4*)go = o0;
        *(float4*)(go + 4) = o1;
    }
}

__global__ void result_kernel(const float* __restrict__ deltas,
                              float* __restrict__ out) {
    if (threadIdx.x == 0) {
        int res = TMAX;
        for (int t = 0; t < TMAX; ++t) {
            if (deltas[t] < EPSC) { res = t; break; }
        }
        out[(size_t)ROWS * HID] = (float)res;
    }
}

// ---------------------------------------------------------------------------
extern "C" void kernel_launch(void* const* d_in, const int* in_sizes, int n_in,
                              void* d_out, int out_size, void* d_ws, size_t ws_size,
                              hipStream_t stream) {
    const float* x  = (const float*)d_in[0];
    const float* Ws = (const float*)d_in[1];
    const float* bs = (const float*)d_in[2];
    const float* bi_dummy = 0; (void)bi_dummy;
    const float* Wi = (const float*)d_in[3];
    const float* bi = (const float*)d_in[4];
    const float* Wt = (const float*)d_in[5];
    const float* bt = (const float*)d_in[6];
    float* out = (float*)d_out;

    char* p = (char*)d_ws;
    u8*    Wf     = (u8*)p;    p += (size_t)NLAYER * TWOH * TWOH;            // 1 MB
    float* bp     = (float*)p; p += (size_t)NLAYER * TWOH * sizeof(float);   // 8 KB
    float* deltas = (float*)p; p += 64 * sizeof(float);

    hipMemsetAsync(deltas, 0, 64 * sizeof(float), stream);
    pack_w_kernel<<<(NLAYER * TWOH * TWOH) / 256, 256, 0, stream>>>(Ws, Wi, Wt, Wf);
    pack_b_kernel<<<(NLAYER * TWOH) / 256, 256, 0, stream>>>(bs, bi, bt, bp);

    persistent_kernel<<<256, 1024, 0, stream>>>(x, Wf, bp, deltas, out);
    result_kernel<<<1, 64, 0, stream>>>(deltas, out);
}

// Round 4
// 5592.498 us; speedup vs baseline: 1.0266x; 1.0005x over previous
//
#include <hip/hip_runtime.h>
#include <math.h>

#define HID 256
#define TWOH 512
#define ROWS 8192   // B*S
#define NLAYER 4
#define TMAX 50
#define DT 0.05f
#define EPSC 1e-3f

typedef float f32x4 __attribute__((ext_vector_type(4)));
typedef long  long2v __attribute__((ext_vector_type(2)));
typedef unsigned char u8;

// fp8 helpers (OCP e4m3 on gfx950)
__device__ inline u8 f32_to_fp8(float v) {
    return (u8)(__builtin_amdgcn_cvt_pk_fp8_f32(v, v, 0, 0) & 0xff);
}
__device__ inline float fp8_to_f32(u8 b) {
    return __builtin_amdgcn_cvt_f32_fp8((int)b, 0);
}

// ---------------------------------------------------------------------------
// Pair-packed fragment-major fp8 weights. Per wave-column-group wv
// (d-range [wv*32, wv*32+32)), fragment-PAIR (L,wv,ci,g) is 1024 B:
// lane's 16 B at lane*16 = { h=0 fragment 8 B | h=1 fragment 8 B } so the
// K-loop loads one dwordx4 per (ci,g) instead of two dwordx2.
//   g=0 -> tau columns, g=1 -> forcing columns; col d = wv*32 + h*16 + l15
//   k = ci*32 + quad*8 + j
// e bits: j:0-2, h:3, lane:4-9, g:10, ci:11-14, wv:15-17, L:18-19.
// tau row d: Wt[d][k]; forcing row d: k<256 ? Wi[d][k] : Ws[d][k-256].
// ---------------------------------------------------------------------------
__global__ void pack_w_kernel(const float* __restrict__ Ws,
                              const float* __restrict__ Wi,
                              const float* __restrict__ Wt,
                              u8* __restrict__ Wf) {
    int e = blockIdx.x * 256 + threadIdx.x;     // [0, 2^20)
    int j    = e & 7;
    int h    = (e >> 3) & 1;
    int lane = (e >> 4) & 63;
    int g    = (e >> 10) & 1;
    int ci   = (e >> 11) & 15;
    int wv   = (e >> 15) & 7;
    int L    = (e >> 18);
    int l15  = lane & 15;
    int quad = lane >> 4;
    int d = wv * 32 + h * 16 + l15;
    int k = ci * 32 + quad * 8 + j;
    float v;
    if (g == 0) {
        v = Wt[(size_t)L * HID * TWOH + (size_t)d * TWOH + k];
    } else {
        v = (k < HID) ? Wi[(size_t)L * HID * HID + (size_t)d * HID + k]
                      : Ws[(size_t)L * HID * HID + (size_t)d * HID + (k - HID)];
    }
    Wf[e] = f32_to_fp8(v);
}

__global__ void pack_b_kernel(const float* __restrict__ bs,
                              const float* __restrict__ bi,
                              const float* __restrict__ bt,
                              float* __restrict__ bp) {
    int idx = blockIdx.x * 256 + threadIdx.x;   // [0, 4*512): L*512 + n
    int L = idx / TWOH;
    int n = idx % TWOH;
    int d = n >> 1;
    bp[idx] = ((n & 1) == 0) ? bt[L * HID + d]
                             : (bs[L * HID + d] + bi[L * HID + d]);
}

// ---------------------------------------------------------------------------
// Persistent kernel: 256 blocks x 1024 threads (16 waves = 2 row-groups x
// 8 col-groups), block owns rows [32b, 32b+32). h state double-buffered in
// LDS (fp8, swizzled) -> ONE barrier per (t,L) stage. h packed in registers
// for the epilogue; biases in LDS.
// __launch_bounds__(1024) with NO min-waves arg: the 1024-thread block
// forces 4 waves/SIMD co-residency -> 128 VGPR budget. (The earlier
// (1024,4) variant clamped the allocator to 64 VGPRs -> scratch spills ->
// 12.7 GB of HBM traffic/launch. Measured R3: FETCH 1.27e7 KB.)
// Weights stream L2 -> registers as 1 KB pair-fragments; the two row-group
// waves of a col-group read the same stream (L1 reuse).
// ---------------------------------------------------------------------------
__global__ __launch_bounds__(1024) void persistent_kernel(
    const float* __restrict__ x,
    const u8* __restrict__ Wf,
    const float* __restrict__ bp,
    float* __restrict__ deltas,
    float* __restrict__ out)
{
    __shared__ u8 sX[32 * 256];                 //  8 KB
    __shared__ u8 sH[2][NLAYER][32 * 256];      // 64 KB (double-buffered)
    __shared__ float2 sBias[NLAYER][256];       //  8 KB (b_tau, b_forcing)
    __shared__ float sRed[16];

    const int tid  = threadIdx.x;
    const int lane = tid & 63;
    const int w    = tid >> 6;               // 0..15
    const int wv   = w & 7;                  // col group (d-base wv*32)
    const int mg   = w >> 3;                 // row group (rows mg*16..+16)
    const int l15  = lane & 15;
    const int quad = lane >> 4;              // 0..3
    const int w32  = wv * 32;
    const size_t rowbase = (size_t)blockIdx.x * 32;

    // ---- stage x -> sX (fp8, swizzled): 32 rows x 32 segs = 1024 units ----
    {
        int r = tid >> 5, seg = tid & 31;
        const float* gx = x + (rowbase + r) * HID + seg * 8;
        float4 v0 = *(const float4*)gx;
        float4 v1 = *(const float4*)(gx + 4);
        int lo = __builtin_amdgcn_cvt_pk_fp8_f32(v0.x, v0.y, 0, 0);
        lo     = __builtin_amdgcn_cvt_pk_fp8_f32(v0.z, v0.w, lo, 1);
        int hi = __builtin_amdgcn_cvt_pk_fp8_f32(v1.x, v1.y, 0, 0);
        hi     = __builtin_amdgcn_cvt_pk_fp8_f32(v1.z, v1.w, hi, 1);
        long pk = ((long)(unsigned int)lo) | ((long)hi << 32);
        *(long*)&sX[r * 256 + (seg ^ r) * 8] = pk;
    }
    // ---- zero both h buffers: 64 KB = 8192 longs ----
    {
        long* hflat = (long*)&sH[0][0][0];
        #pragma unroll
        for (int it = 0; it < 8; ++it) hflat[tid + it * 1024] = 0;
    }
    // ---- bias table -> LDS: 1024 entries, one per thread ----
    sBias[tid >> 8][tid & 255] =
        *(const float2*)(bp + (tid >> 8) * TWOH + 2 * (tid & 255));

    // ---- packed fp8 h state for this lane's 8 outputs per layer ----
    int hpk[NLAYER][2] = {};   // [L][ntp], byte r = row mg*16+quad*4+r

    __syncthreads();

    #pragma unroll 1
    for (int t = 0; t < TMAX; ++t) {
        const int rs = t & 1, ws = rs ^ 1;
        float dmax = 0.0f;
        #pragma unroll
        for (int L = 0; L < NLAYER; ++L) {
            const u8* Alo = (L == 0) ? sX : &sH[ws][L - 1][0];  // cur_in (k<256)
            const u8* Ahi = &sH[rs][L][0];                      // h_prev (k>=256)
            u8*       Hout = &sH[ws][L][0];
            // wave's pair-fragment stream: 32 KB contiguous per (L, wv)
            const u8* wb = Wf + ((size_t)(L * 8 + wv) << 15) + (size_t)lane * 16;

            f32x4 acc[4];   // 0: tau ntp0, 1: tau ntp1, 2: forc ntp0, 3: forc ntp1
            #pragma unroll
            for (int n = 0; n < 4; ++n) acc[n] = (f32x4){0.f, 0.f, 0.f, 0.f};

            // depth-2 register prefetch of B pair-fragments (1 KB each)
            long2v bb[2][2];
            #pragma unroll
            for (int pi = 0; pi < 2; ++pi)
                #pragma unroll
                for (int g = 0; g < 2; ++g)
                    bb[pi][g] = *(const long2v*)(wb + (size_t)((pi * 2 + g) << 10));

            const int row = mg * 16 + l15;
            #pragma unroll
            for (int ci = 0; ci < 16; ++ci) {            // k = 32*ci
                const int p = ci & 1;
                const u8* Asrc = (ci < 8) ? Alo : Ahi;   // static under unroll
                const int seg = (ci & 7) * 4 + quad;     // 8-B seg in [0,32)
                long a = *(const long*)&Asrc[row * 256 + (seg ^ row) * 8];
                acc[0] = __builtin_amdgcn_mfma_f32_16x16x32_fp8_fp8(a, bb[p][0][0], acc[0], 0, 0, 0);
                acc[1] = __builtin_amdgcn_mfma_f32_16x16x32_fp8_fp8(a, bb[p][0][1], acc[1], 0, 0, 0);
                acc[2] = __builtin_amdgcn_mfma_f32_16x16x32_fp8_fp8(a, bb[p][1][0], acc[2], 0, 0, 0);
                acc[3] = __builtin_amdgcn_mfma_f32_16x16x32_fp8_fp8(a, bb[p][1][1], acc[3], 0, 0, 0);
                if (ci + 2 < 16) {
                    #pragma unroll
                    for (int g = 0; g < 2; ++g)
                        bb[p][g] = *(const long2v*)(wb + (size_t)(((ci + 2) * 2 + g) << 10));
                }
            }

            // Epilogue. C/D: col = l15 (tile ntp), row = mg*16 + quad*4 + r.
            // h_prev from registers (bit-identical to the LDS fp8 bytes).
            #pragma unroll
            for (int ntp = 0; ntp < 2; ++ntp) {
                const int d = w32 + ntp * 16 + l15;
                const float2 b2 = sBias[L][d];
                const int seg = d >> 3, dlow = d & 7;
                const int hold = hpk[L][ntp];
                int hnew = 0;
                #pragma unroll
                for (int r = 0; r < 4; ++r) {
                    float tpre = acc[ntp][r]     + b2.x;
                    float fpre = acc[ntp + 2][r] + b2.y;
                    tpre = fminf(30.f, fmaxf(-30.f, tpre));
                    fpre = fminf(15.f, fmaxf(-15.f, fpre));
                    // h/(sigma(t)+1e-6) == h*(1+u)/(1+eps+eps*u), u=e^-t
                    float u   = __expf(-tpre);
                    float den = 1.0f + 1e-6f + 1e-6f * u;
                    float rcp = __builtin_amdgcn_rcpf(den);
                    float e2  = __expf(2.0f * fpre);
                    float r2  = __builtin_amdgcn_rcpf(e2 + 1.0f);
                    float fo  = (e2 - 1.0f) * r2;
                    float h   = fp8_to_f32((u8)(hold >> (8 * r)));
                    float gq  = h * (1.0f + u) * rcp;
                    float nv  = h + DT * (fo - gq);
                    nv = fminf(10.0f, fmaxf(-10.0f, nv));
                    u8 byte = f32_to_fp8(nv);
                    hnew |= ((int)byte) << (8 * r);
                    const int orow = mg * 16 + quad * 4 + r;
                    Hout[orow * 256 + (seg ^ orow) * 8 + dlow] = byte;
                    dmax = fmaxf(dmax, fabsf(nv - h));
                }
                hpk[L][ntp] = hnew;
            }
            if (L == NLAYER - 1) {
                #pragma unroll
                for (int off = 32; off > 0; off >>= 1)
                    dmax = fmaxf(dmax, __shfl_xor(dmax, off));
                if (lane == 0) sRed[w] = dmax;
            }
            __syncthreads();   // ws[L] (and sRed) visible; only barrier/stage
        } // L

        if (tid == 0) {
            float m = sRed[0];
            #pragma unroll
            for (int i = 1; i < 16; ++i) m = fmaxf(m, sRed[i]);
            atomicMax((unsigned int*)(deltas + t), __float_as_uint(m));
        }
    } // t

    // ---- final output: layer-3 states from write-side of t=TMAX-1 ----
    {
        const u8* fin = &sH[((TMAX - 1) & 1) ^ 1][NLAYER - 1][0];
        int r = tid >> 5, seg = tid & 31;
        long v = *(const long*)&fin[r * 256 + (seg ^ r) * 8];
        int lo = (int)(v & 0xffffffffl);
        int hi = (int)(v >> 32);
        float* go = out + (rowbase + r) * HID + seg * 8;
        float4 o0, o1;
        o0.x = __builtin_amdgcn_cvt_f32_fp8(lo, 0);
        o0.y = __builtin_amdgcn_cvt_f32_fp8(lo, 1);
        o0.z = __builtin_amdgcn_cvt_f32_fp8(lo, 2);
        o0.w = __builtin_amdgcn_cvt_f32_fp8(lo, 3);
        o1.x = __builtin_amdgcn_cvt_f32_fp8(hi, 0);
        o1.y = __builtin_amdgcn_cvt_f32_fp8(hi, 1);
        o1.z = __builtin_amdgcn_cvt_f32_fp8(hi, 2);
        o1.w = __builtin_amdgcn_cvt_f32_fp8(hi, 3);
        *(float4*)go = o0;
        *(float4*)(go + 4) = o1;
    }
}

__global__ void result_kernel(const float* __restrict__ deltas,
                              float* __restrict__ out) {
    if (threadIdx.x == 0) {
        int res = TMAX;
        for (int t = 0; t < TMAX; ++t) {
            if (deltas[t] < EPSC) { res = t; break; }
        }
        out[(size_t)ROWS * HID] = (float)res;
    }
}

// ---------------------------------------------------------------------------
extern "C" void kernel_launch(void* const* d_in, const int* in_sizes, int n_in,
                              void* d_out, int out_size, void* d_ws, size_t ws_size,
                              hipStream_t stream) {
    const float* x  = (const float*)d_in[0];
    const float* Ws = (const float*)d_in[1];
    const float* bs = (const float*)d_in[2];
    const float* Wi = (const float*)d_in[3];
    const float* bi = (const float*)d_in[4];
    const float* Wt = (const float*)d_in[5];
    const float* bt = (const float*)d_in[6];
    float* out = (float*)d_out;

    char* p = (char*)d_ws;
    u8*    Wf     = (u8*)p;    p += (size_t)NLAYER * TWOH * TWOH;            // 1 MB
    float* bp     = (float*)p; p += (size_t)NLAYER * TWOH * sizeof(float);   // 8 KB
    float* deltas = (float*)p; p += 64 * sizeof(float);

    hipMemsetAsync(deltas, 0, 64 * sizeof(float), stream);
    pack_w_kernel<<<(NLAYER * TWOH * TWOH) / 256, 256, 0, stream>>>(Ws, Wi, Wt, Wf);
    pack_b_kernel<<<(NLAYER * TWOH) / 256, 256, 0, stream>>>(bs, bi, bt, bp);

    persistent_kernel<<<256, 1024, 0, stream>>>(x, Wf, bp, deltas, out);
    result_kernel<<<1, 64, 0, stream>>>(deltas, out);
}

// Round 5
// 5590.673 us; speedup vs baseline: 1.0269x; 1.0003x over previous
//
#include <hip/hip_runtime.h>
#include <math.h>

#define HID 256
#define TWOH 512
#define ROWS 8192   // B*S
#define NLAYER 4
#define TMAX 50
#define DT 0.05f
#define EPSC 1e-3f

typedef float f32x4 __attribute__((ext_vector_type(4)));
typedef long  long2v __attribute__((ext_vector_type(2)));
typedef unsigned char u8;

// fp8 helpers (OCP e4m3 on gfx950)
__device__ inline u8 f32_to_fp8(float v) {
    return (u8)(__builtin_amdgcn_cvt_pk_fp8_f32(v, v, 0, 0) & 0xff);
}
__device__ inline float fp8_to_f32(u8 b) {
    return __builtin_amdgcn_cvt_f32_fp8((int)b, 0);
}

// ---------------------------------------------------------------------------
// Pair-packed fragment-major fp8 weights. Per wave-column-group wv
// (d-range [wv*32, wv*32+32)), fragment-PAIR (L,wv,ci,g) is 1024 B:
// lane's 16 B at lane*16 = { h=0 fragment 8 B | h=1 fragment 8 B } so the
// K-loop loads one dwordx4 per (ci,g) instead of two dwordx2.
//   g=0 -> tau columns, g=1 -> forcing columns; col d = wv*32 + h*16 + l15
//   k = ci*32 + quad*8 + j
// e bits: j:0-2, h:3, lane:4-9, g:10, ci:11-14, wv:15-17, L:18-19.
// tau row d: Wt[d][k]; forcing row d: k<256 ? Wi[d][k] : Ws[d][k-256].
// ---------------------------------------------------------------------------
__global__ void pack_w_kernel(const float* __restrict__ Ws,
                              const float* __restrict__ Wi,
                              const float* __restrict__ Wt,
                              u8* __restrict__ Wf) {
    int e = blockIdx.x * 256 + threadIdx.x;     // [0, 2^20)
    int j    = e & 7;
    int h    = (e >> 3) & 1;
    int lane = (e >> 4) & 63;
    int g    = (e >> 10) & 1;
    int ci   = (e >> 11) & 15;
    int wv   = (e >> 15) & 7;
    int L    = (e >> 18);
    int l15  = lane & 15;
    int quad = lane >> 4;
    int d = wv * 32 + h * 16 + l15;
    int k = ci * 32 + quad * 8 + j;
    float v;
    if (g == 0) {
        v = Wt[(size_t)L * HID * TWOH + (size_t)d * TWOH + k];
    } else {
        v = (k < HID) ? Wi[(size_t)L * HID * HID + (size_t)d * HID + k]
                      : Ws[(size_t)L * HID * HID + (size_t)d * HID + (k - HID)];
    }
    Wf[e] = f32_to_fp8(v);
}

__global__ void pack_b_kernel(const float* __restrict__ bs,
                              const float* __restrict__ bi,
                              const float* __restrict__ bt,
                              float* __restrict__ bp) {
    int idx = blockIdx.x * 256 + threadIdx.x;   // [0, 4*512): L*512 + n
    int L = idx / TWOH;
    int n = idx % TWOH;
    int d = n >> 1;
    bp[idx] = ((n & 1) == 0) ? bt[L * HID + d]
                             : (bs[L * HID + d] + bi[L * HID + d]);
}

// ---------------------------------------------------------------------------
// Persistent kernel: 256 blocks x 1024 threads (16 waves = 2 row-groups x
// 8 col-groups), block owns rows [32b, 32b+32). h state double-buffered in
// LDS (fp8, swizzled) -> ONE barrier per (t,L) stage. h packed in registers
// for the epilogue; biases in LDS.
// amdgpu_waves_per_eu(4,4): pin the occupancy TARGET (not just the min) to
// 4 waves/EU -> 128-VGPR allocation budget. R2-R4 measured: without the max
// bound the allocator budgets for 8 waves/EU = 64 VGPRs and spills ~200 B of
// loop-invariants per thread -> 12.7 GB/launch of scratch-reload HBM traffic
// (FETCH 1.27e7 KB, 24:1 read:write). LDS (82 KB) already caps occupancy at
// 1 block = 4 waves/EU, so nothing is lost.
// Weights stream L2 -> registers as 1 KB pair-fragments; the two row-group
// waves of a col-group read the same stream (L1 reuse).
// ---------------------------------------------------------------------------
__global__ __launch_bounds__(1024)
__attribute__((amdgpu_waves_per_eu(4, 4)))
void persistent_kernel(
    const float* __restrict__ x,
    const u8* __restrict__ Wf,
    const float* __restrict__ bp,
    float* __restrict__ deltas,
    float* __restrict__ out)
{
    __shared__ u8 sX[32 * 256];                 //  8 KB
    __shared__ u8 sH[2][NLAYER][32 * 256];      // 64 KB (double-buffered)
    __shared__ float2 sBias[NLAYER][256];       //  8 KB (b_tau, b_forcing)
    __shared__ float sRed[16];

    const int tid  = threadIdx.x;
    const int lane = tid & 63;
    const int w    = tid >> 6;               // 0..15
    const int wv   = w & 7;                  // col group (d-base wv*32)
    const int mg   = w >> 3;                 // row group (rows mg*16..+16)
    const int l15  = lane & 15;
    const int quad = lane >> 4;              // 0..3
    const int w32  = wv * 32;
    const size_t rowbase = (size_t)blockIdx.x * 32;

    // ---- stage x -> sX (fp8, swizzled): 32 rows x 32 segs = 1024 units ----
    {
        int r = tid >> 5, seg = tid & 31;
        const float* gx = x + (rowbase + r) * HID + seg * 8;
        float4 v0 = *(const float4*)gx;
        float4 v1 = *(const float4*)(gx + 4);
        int lo = __builtin_amdgcn_cvt_pk_fp8_f32(v0.x, v0.y, 0, 0);
        lo     = __builtin_amdgcn_cvt_pk_fp8_f32(v0.z, v0.w, lo, 1);
        int hi = __builtin_amdgcn_cvt_pk_fp8_f32(v1.x, v1.y, 0, 0);
        hi     = __builtin_amdgcn_cvt_pk_fp8_f32(v1.z, v1.w, hi, 1);
        long pk = ((long)(unsigned int)lo) | ((long)hi << 32);
        *(long*)&sX[r * 256 + (seg ^ r) * 8] = pk;
    }
    // ---- zero both h buffers: 64 KB = 8192 longs ----
    {
        long* hflat = (long*)&sH[0][0][0];
        #pragma unroll
        for (int it = 0; it < 8; ++it) hflat[tid + it * 1024] = 0;
    }
    // ---- bias table -> LDS: 1024 entries, one per thread ----
    sBias[tid >> 8][tid & 255] =
        *(const float2*)(bp + (tid >> 8) * TWOH + 2 * (tid & 255));

    // ---- packed fp8 h state for this lane's 8 outputs per layer ----
    int hpk[NLAYER][2] = {};   // [L][ntp], byte r = row mg*16+quad*4+r

    __syncthreads();

    #pragma unroll 1
    for (int t = 0; t < TMAX; ++t) {
        const int rs = t & 1, ws = rs ^ 1;
        float dmax = 0.0f;
        #pragma unroll
        for (int L = 0; L < NLAYER; ++L) {
            const u8* Alo = (L == 0) ? sX : &sH[ws][L - 1][0];  // cur_in (k<256)
            const u8* Ahi = &sH[rs][L][0];                      // h_prev (k>=256)
            u8*       Hout = &sH[ws][L][0];
            // wave's pair-fragment stream: 32 KB contiguous per (L, wv)
            const u8* wb = Wf + ((size_t)(L * 8 + wv) << 15) + (size_t)lane * 16;

            f32x4 acc[4];   // 0: tau ntp0, 1: tau ntp1, 2: forc ntp0, 3: forc ntp1
            #pragma unroll
            for (int n = 0; n < 4; ++n) acc[n] = (f32x4){0.f, 0.f, 0.f, 0.f};

            // depth-2 register prefetch of B pair-fragments (1 KB each)
            long2v bb[2][2];
            #pragma unroll
            for (int pi = 0; pi < 2; ++pi)
                #pragma unroll
                for (int g = 0; g < 2; ++g)
                    bb[pi][g] = *(const long2v*)(wb + (size_t)((pi * 2 + g) << 10));

            const int row = mg * 16 + l15;
            #pragma unroll
            for (int ci = 0; ci < 16; ++ci) {            // k = 32*ci
                const int p = ci & 1;
                const u8* Asrc = (ci < 8) ? Alo : Ahi;   // static under unroll
                const int seg = (ci & 7) * 4 + quad;     // 8-B seg in [0,32)
                long a = *(const long*)&Asrc[row * 256 + (seg ^ row) * 8];
                acc[0] = __builtin_amdgcn_mfma_f32_16x16x32_fp8_fp8(a, bb[p][0][0], acc[0], 0, 0, 0);
                acc[1] = __builtin_amdgcn_mfma_f32_16x16x32_fp8_fp8(a, bb[p][0][1], acc[1], 0, 0, 0);
                acc[2] = __builtin_amdgcn_mfma_f32_16x16x32_fp8_fp8(a, bb[p][1][0], acc[2], 0, 0, 0);
                acc[3] = __builtin_amdgcn_mfma_f32_16x16x32_fp8_fp8(a, bb[p][1][1], acc[3], 0, 0, 0);
                if (ci + 2 < 16) {
                    #pragma unroll
                    for (int g = 0; g < 2; ++g)
                        bb[p][g] = *(const long2v*)(wb + (size_t)(((ci + 2) * 2 + g) << 10));
                }
            }

            // Epilogue. C/D: col = l15 (tile ntp), row = mg*16 + quad*4 + r.
            // h_prev from registers (bit-identical to the LDS fp8 bytes).
            #pragma unroll
            for (int ntp = 0; ntp < 2; ++ntp) {
                const int d = w32 + ntp * 16 + l15;
                const float2 b2 = sBias[L][d];
                const int seg = d >> 3, dlow = d & 7;
                const int hold = hpk[L][ntp];
                int hnew = 0;
                #pragma unroll
                for (int r = 0; r < 4; ++r) {
                    float tpre = acc[ntp][r]     + b2.x;
                    float fpre = acc[ntp + 2][r] + b2.y;
                    tpre = fminf(30.f, fmaxf(-30.f, tpre));
                    fpre = fminf(15.f, fmaxf(-15.f, fpre));
                    // h/(sigma(t)+1e-6) == h*(1+u)/(1+eps+eps*u), u=e^-t
                    float u   = __expf(-tpre);
                    float den = 1.0f + 1e-6f + 1e-6f * u;
                    float rcp = __builtin_amdgcn_rcpf(den);
                    float e2  = __expf(2.0f * fpre);
                    float r2  = __builtin_amdgcn_rcpf(e2 + 1.0f);
                    float fo  = (e2 - 1.0f) * r2;
                    float h   = fp8_to_f32((u8)(hold >> (8 * r)));
                    float gq  = h * (1.0f + u) * rcp;
                    float nv  = h + DT * (fo - gq);
                    nv = fminf(10.0f, fmaxf(-10.0f, nv));
                    u8 byte = f32_to_fp8(nv);
                    hnew |= ((int)byte) << (8 * r);
                    const int orow = mg * 16 + quad * 4 + r;
                    Hout[orow * 256 + (seg ^ orow) * 8 + dlow] = byte;
                    dmax = fmaxf(dmax, fabsf(nv - h));
                }
                hpk[L][ntp] = hnew;
            }
            if (L == NLAYER - 1) {
                #pragma unroll
                for (int off = 32; off > 0; off >>= 1)
                    dmax = fmaxf(dmax, __shfl_xor(dmax, off));
                if (lane == 0) sRed[w] = dmax;
            }
            __syncthreads();   // ws[L] (and sRed) visible; only barrier/stage
        } // L

        if (tid == 0) {
            float m = sRed[0];
            #pragma unroll
            for (int i = 1; i < 16; ++i) m = fmaxf(m, sRed[i]);
            atomicMax((unsigned int*)(deltas + t), __float_as_uint(m));
        }
    } // t

    // ---- final output: layer-3 states from write-side of t=TMAX-1 ----
    {
        const u8* fin = &sH[((TMAX - 1) & 1) ^ 1][NLAYER - 1][0];
        int r = tid >> 5, seg = tid & 31;
        long v = *(const long*)&fin[r * 256 + (seg ^ r) * 8];
        int lo = (int)(v & 0xffffffffl);
        int hi = (int)(v >> 32);
        float* go = out + (rowbase + r) * HID + seg * 8;
        float4 o0, o1;
        o0.x = __builtin_amdgcn_cvt_f32_fp8(lo, 0);
        o0.y = __builtin_amdgcn_cvt_f32_fp8(lo, 1);
        o0.z = __builtin_amdgcn_cvt_f32_fp8(lo, 2);
        o0.w = __builtin_amdgcn_cvt_f32_fp8(lo, 3);
        o1.x = __builtin_amdgcn_cvt_f32_fp8(hi, 0);
        o1.y = __builtin_amdgcn_cvt_f32_fp8(hi, 1);
        o1.z = __builtin_amdgcn_cvt_f32_fp8(hi, 2);
        o1.w = __builtin_amdgcn_cvt_f32_fp8(hi, 3);
        *(float4*)go = o0;
        *(float4*)(go + 4) = o1;
    }
}

__global__ void result_kernel(const float* __restrict__ deltas,
                              float* __restrict__ out) {
    if (threadIdx.x == 0) {
        int res = TMAX;
        for (int t = 0; t < TMAX; ++t) {
            if (deltas[t] < EPSC) { res = t; break; }
        }
        out[(size_t)ROWS * HID] = (float)res;
    }
}

// ---------------------------------------------------------------------------
extern "C" void kernel_launch(void* const* d_in, const int* in_sizes, int n_in,
                              void* d_out, int out_size, void* d_ws, size_t ws_size,
                              hipStream_t stream) {
    const float* x  = (const float*)d_in[0];
    const float* Ws = (const float*)d_in[1];
    const float* bs = (const float*)d_in[2];
    const float* Wi = (const float*)d_in[3];
    const float* bi = (const float*)d_in[4];
    const float* Wt = (const float*)d_in[5];
    const float* bt = (const float*)d_in[6];
    float* out = (float*)d_out;

    char* p = (char*)d_ws;
    u8*    Wf     = (u8*)p;    p += (size_t)NLAYER * TWOH * TWOH;            // 1 MB
    float* bp     = (float*)p; p += (size_t)NLAYER * TWOH * sizeof(float);   // 8 KB
    float* deltas = (float*)p; p += 64 * sizeof(float);

    hipMemsetAsync(deltas, 0, 64 * sizeof(float), stream);
    pack_w_kernel<<<(NLAYER * TWOH * TWOH) / 256, 256, 0, stream>>>(Ws, Wi, Wt, Wf);
    pack_b_kernel<<<(NLAYER * TWOH) / 256, 256, 0, stream>>>(bs, bi, bt, bp);

    persistent_kernel<<<256, 1024, 0, stream>>>(x, Wf, bp, deltas, out);
    result_kernel<<<1, 64, 0, stream>>>(deltas, out);
}

// Round 6
// 2377.319 us; speedup vs baseline: 2.4149x; 2.3517x over previous
//
#include <hip/hip_runtime.h>
#include <math.h>

#define HID 256
#define TWOH 512
#define ROWS 8192   // B*S
#define NLAYER 4
#define TMAX 50
#define DT 0.05f
#define EPSC 1e-3f

typedef float f32x4 __attribute__((ext_vector_type(4)));
typedef long  long2v __attribute__((ext_vector_type(2)));
typedef unsigned char u8;

// fp8 helpers (OCP e4m3 on gfx950)
__device__ inline u8 f32_to_fp8(float v) {
    return (u8)(__builtin_amdgcn_cvt_pk_fp8_f32(v, v, 0, 0) & 0xff);
}
__device__ inline float fp8_to_f32(u8 b) {
    return __builtin_amdgcn_cvt_f32_fp8((int)b, 0);
}

// ---------------------------------------------------------------------------
// Pair-packed fragment-major fp8 weights. Per wave-column-group wv
// (d-range [wv*32, wv*32+32)), fragment-PAIR (L,wv,ci,g) is 1024 B:
// lane's 16 B at lane*16 = { h=0 fragment 8 B | h=1 fragment 8 B } so the
// K-loop loads one dwordx4 per (ci,g) instead of two dwordx2.
//   g=0 -> tau columns, g=1 -> forcing columns; col d = wv*32 + h*16 + l15
//   k = ci*32 + quad*8 + j
// e bits: j:0-2, h:3, lane:4-9, g:10, ci:11-14, wv:15-17, L:18-19.
// tau row d: Wt[d][k]; forcing row d: k<256 ? Wi[d][k] : Ws[d][k-256].
// ---------------------------------------------------------------------------
__global__ void pack_w_kernel(const float* __restrict__ Ws,
                              const float* __restrict__ Wi,
                              const float* __restrict__ Wt,
                              u8* __restrict__ Wf) {
    int e = blockIdx.x * 256 + threadIdx.x;     // [0, 2^20)
    int j    = e & 7;
    int h    = (e >> 3) & 1;
    int lane = (e >> 4) & 63;
    int g    = (e >> 10) & 1;
    int ci   = (e >> 11) & 15;
    int wv   = (e >> 15) & 7;
    int L    = (e >> 18);
    int l15  = lane & 15;
    int quad = lane >> 4;
    int d = wv * 32 + h * 16 + l15;
    int k = ci * 32 + quad * 8 + j;
    float v;
    if (g == 0) {
        v = Wt[(size_t)L * HID * TWOH + (size_t)d * TWOH + k];
    } else {
        v = (k < HID) ? Wi[(size_t)L * HID * HID + (size_t)d * HID + k]
                      : Ws[(size_t)L * HID * HID + (size_t)d * HID + (k - HID)];
    }
    Wf[e] = f32_to_fp8(v);
}

__global__ void pack_b_kernel(const float* __restrict__ bs,
                              const float* __restrict__ bi,
                              const float* __restrict__ bt,
                              float* __restrict__ bp) {
    int idx = blockIdx.x * 256 + threadIdx.x;   // [0, 4*512): L*512 + n
    int L = idx / TWOH;
    int n = idx % TWOH;
    int d = n >> 1;
    bp[idx] = ((n & 1) == 0) ? bt[L * HID + d]
                             : (bs[L * HID + d] + bi[L * HID + d]);
}

// ---------------------------------------------------------------------------
// Persistent kernel: 256 blocks x 512 threads (8 waves, one col-group each;
// every wave computes both 16-row tiles mt=0,1). Block owns rows [32b,32b+32).
// This is the R0-proven register shape (96 VGPR, no spill; the 1024-thread
// variants all spilled at a 64-VGPR clamp -> 12.7 GB scratch traffic).
//
// New vs R0: h state double-buffered in LDS (rs=read of t, ws=write of t),
// which makes the upper K-half (ci 8..15, A = h_prev = sH[rs][L]) independent
// of the previous stage's epilogue. Stage structure:
//     upper-K (8 ci)  |  barrier  |  lower-K (8 ci)  |  epilogue
// with NO barrier after the epilogue: 200 barriers total (R0: 400), and the
// lower-K + epilogue + next-stage upper-K run un-barriered so waves skew and
// MFMA overlaps epilogue VALU across waves. Per-wave atomicMax on deltas[t]
// replaces the sRed + tid0 reduction (no end-of-t barrier needed).
// ---------------------------------------------------------------------------
__global__ __launch_bounds__(512, 1) void persistent_kernel(
    const float* __restrict__ x,
    const u8* __restrict__ Wf,
    const float* __restrict__ bp,
    float* __restrict__ deltas,
    float* __restrict__ out)
{
    __shared__ u8 sX[32 * 256];                 //  8 KB
    __shared__ u8 sH[2][NLAYER][32 * 256];      // 64 KB (double-buffered)
    __shared__ float2 sBias[NLAYER][256];       //  8 KB (b_tau, b_forcing)

    const int tid  = threadIdx.x;
    const int lane = tid & 63;
    const int wv   = tid >> 6;               // 0..7 col group (d-base wv*32)
    const int l15  = lane & 15;
    const int quad = lane >> 4;              // 0..3
    const int w32  = wv * 32;
    const size_t rowbase = (size_t)blockIdx.x * 32;

    // ---- stage x -> sX (fp8, swizzled): 32 rows x 32 segs = 1024 units ----
    #pragma unroll
    for (int it = 0; it < 2; ++it) {
        int s = tid + it * 512;
        int r = s >> 5, seg = s & 31;
        const float* gx = x + (rowbase + r) * HID + seg * 8;
        float4 v0 = *(const float4*)gx;
        float4 v1 = *(const float4*)(gx + 4);
        int lo = __builtin_amdgcn_cvt_pk_fp8_f32(v0.x, v0.y, 0, 0);
        lo     = __builtin_amdgcn_cvt_pk_fp8_f32(v0.z, v0.w, lo, 1);
        int hi = __builtin_amdgcn_cvt_pk_fp8_f32(v1.x, v1.y, 0, 0);
        hi     = __builtin_amdgcn_cvt_pk_fp8_f32(v1.z, v1.w, hi, 1);
        long pk = ((long)(unsigned int)lo) | ((long)hi << 32);
        *(long*)&sX[r * 256 + (seg ^ r) * 8] = pk;
    }
    // ---- zero both h buffers: 64 KB = 8192 longs ----
    {
        long* hflat = (long*)&sH[0][0][0];
        #pragma unroll
        for (int it = 0; it < 16; ++it) hflat[tid + it * 512] = 0;
    }
    // ---- bias table -> LDS: 1024 entries ----
    #pragma unroll
    for (int it = 0; it < 2; ++it) {
        int i = tid + it * 512;
        sBias[i >> 8][i & 255] = *(const float2*)(bp + (i >> 8) * TWOH + 2 * (i & 255));
    }

    __syncthreads();

    #pragma unroll 1
    for (int t = 0; t < TMAX; ++t) {
        const int rs = t & 1, ws = rs ^ 1;
        float dmax = 0.0f;
        #pragma unroll
        for (int L = 0; L < NLAYER; ++L) {
            const u8* Ahi = &sH[rs][L][0];                      // h_prev (k>=256)
            const u8* Alo = (L == 0) ? sX : &sH[ws][L - 1][0];  // cur_in (k<256)
            u8*       Hout = &sH[ws][L][0];
            // wave's pair-fragment stream: 32 KB contiguous per (L, wv)
            const u8* wb = Wf + ((size_t)(L * 8 + wv) << 15) + (size_t)lane * 16;

            f32x4 acc[2][4];   // [mt][0:tau ntp0, 1:tau ntp1, 2:forc ntp0, 3:forc ntp1]
            #pragma unroll
            for (int mt = 0; mt < 2; ++mt)
                #pragma unroll
                for (int n = 0; n < 4; ++n)
                    acc[mt][n] = (f32x4){0.f, 0.f, 0.f, 0.f};

            // K-step order: ci = 8..15 (h_prev half, pre-barrier), then 0..7.
            // depth-2 register prefetch of B pair-fragments (1 KB each).
            long2v bb[2][2];
            #pragma unroll
            for (int pi = 0; pi < 2; ++pi)
                #pragma unroll
                for (int g = 0; g < 2; ++g)
                    bb[pi][g] = *(const long2v*)(wb + (size_t)(((8 + pi) * 2 + g) << 10));

            #pragma unroll
            for (int s = 0; s < 16; ++s) {
                const int ci = (s < 8) ? (s + 8) : (s - 8);
                const int p = s & 1;
                if (s == 8) __syncthreads();   // sH[ws][L-1] now published
                const u8* Asrc = (s < 8) ? Ahi : Alo;   // static under unroll
                const int seg = (ci & 7) * 4 + quad;    // 8-B seg in [0,32)
                long a[2];
                #pragma unroll
                for (int mt = 0; mt < 2; ++mt) {
                    const int row = mt * 16 + l15;
                    a[mt] = *(const long*)&Asrc[row * 256 + (seg ^ row) * 8];
                }
                #pragma unroll
                for (int mt = 0; mt < 2; ++mt)
                    #pragma unroll
                    for (int n = 0; n < 4; ++n)
                        acc[mt][n] = __builtin_amdgcn_mfma_f32_16x16x32_fp8_fp8(
                            a[mt], bb[p][n >> 1][n & 1], acc[mt][n], 0, 0, 0);
                if (s + 2 < 16) {
                    const int nci = (s + 2 < 8) ? (s + 10) : (s - 6);
                    #pragma unroll
                    for (int g = 0; g < 2; ++g)
                        bb[p][g] = *(const long2v*)(wb + (size_t)((nci * 2 + g) << 10));
                }
            }

            // Epilogue. C/D: col = l15 (tile ntp), row = mt*16 + quad*4 + r.
            // Old h read from rs buffer (bit-identical to pre-overwrite bytes);
            // new h written to ws buffer. No barrier after (next stage's
            // mid-barrier protects the lower-K readers).
            #pragma unroll
            for (int ntp = 0; ntp < 2; ++ntp) {
                const int d = w32 + ntp * 16 + l15;
                const float2 b2 = sBias[L][d];
                const int seg = d >> 3, dlow = d & 7;
                #pragma unroll
                for (int mt = 0; mt < 2; ++mt) {
                    #pragma unroll
                    for (int r = 0; r < 4; ++r) {
                        float tpre = acc[mt][ntp][r]     + b2.x;
                        float fpre = acc[mt][ntp + 2][r] + b2.y;
                        tpre = fminf(30.f, fmaxf(-30.f, tpre));
                        fpre = fminf(15.f, fmaxf(-15.f, fpre));
                        // h/(sigma(t)+1e-6) == h*(1+u)/(1+eps+eps*u), u=e^-t
                        float u   = __expf(-tpre);
                        float den = 1.0f + 1e-6f + 1e-6f * u;
                        float rcp = __builtin_amdgcn_rcpf(den);
                        float e2  = __expf(2.0f * fpre);
                        float r2  = __builtin_amdgcn_rcpf(e2 + 1.0f);
                        float fo  = (e2 - 1.0f) * r2;
                        const int row = mt * 16 + quad * 4 + r;
                        const int idx = row * 256 + (seg ^ row) * 8 + dlow;
                        float h  = fp8_to_f32(Ahi[idx]);
                        float gq = h * (1.0f + u) * rcp;
                        float nv = h + DT * (fo - gq);
                        nv = fminf(10.0f, fmaxf(-10.0f, nv));
                        Hout[idx] = f32_to_fp8(nv);
                        dmax = fmaxf(dmax, fabsf(nv - h));
                    }
                }
            }
            if (L == NLAYER - 1) {
                #pragma unroll
                for (int off = 32; off > 0; off >>= 1)
                    dmax = fmaxf(dmax, __shfl_xor(dmax, off));
                if (lane == 0)
                    atomicMax((unsigned int*)(deltas + t), __float_as_uint(dmax));
            }
        } // L
    } // t

    __syncthreads();   // all epilogue writes of t=TMAX-1 visible

    // ---- final output: layer-3 states from write-side of t=TMAX-1 ----
    {
        const u8* fin = &sH[((TMAX - 1) & 1) ^ 1][NLAYER - 1][0];
        #pragma unroll
        for (int it = 0; it < 2; ++it) {
            int s = tid + it * 512;
            int r = s >> 5, seg = s & 31;
            long v = *(const long*)&fin[r * 256 + (seg ^ r) * 8];
            int lo = (int)(v & 0xffffffffl);
            int hi = (int)(v >> 32);
            float* go = out + (rowbase + r) * HID + seg * 8;
            float4 o0, o1;
            o0.x = __builtin_amdgcn_cvt_f32_fp8(lo, 0);
            o0.y = __builtin_amdgcn_cvt_f32_fp8(lo, 1);
            o0.z = __builtin_amdgcn_cvt_f32_fp8(lo, 2);
            o0.w = __builtin_amdgcn_cvt_f32_fp8(lo, 3);
            o1.x = __builtin_amdgcn_cvt_f32_fp8(hi, 0);
            o1.y = __builtin_amdgcn_cvt_f32_fp8(hi, 1);
            o1.z = __builtin_amdgcn_cvt_f32_fp8(hi, 2);
            o1.w = __builtin_amdgcn_cvt_f32_fp8(hi, 3);
            *(float4*)go = o0;
            *(float4*)(go + 4) = o1;
        }
    }
}

__global__ void result_kernel(const float* __restrict__ deltas,
                              float* __restrict__ out) {
    if (threadIdx.x == 0) {
        int res = TMAX;
        for (int t = 0; t < TMAX; ++t) {
            if (deltas[t] < EPSC) { res = t; break; }
        }
        out[(size_t)ROWS * HID] = (float)res;
    }
}

// ---------------------------------------------------------------------------
extern "C" void kernel_launch(void* const* d_in, const int* in_sizes, int n_in,
                              void* d_out, int out_size, void* d_ws, size_t ws_size,
                              hipStream_t stream) {
    const float* x  = (const float*)d_in[0];
    const float* Ws = (const float*)d_in[1];
    const float* bs = (const float*)d_in[2];
    const float* Wi = (const float*)d_in[3];
    const float* bi = (const float*)d_in[4];
    const float* Wt = (const float*)d_in[5];
    const float* bt = (const float*)d_in[6];
    float* out = (float*)d_out;

    char* p = (char*)d_ws;
    u8*    Wf     = (u8*)p;    p += (size_t)NLAYER * TWOH * TWOH;            // 1 MB
    float* bp     = (float*)p; p += (size_t)NLAYER * TWOH * sizeof(float);   // 8 KB
    float* deltas = (float*)p; p += 64 * sizeof(float);

    hipMemsetAsync(deltas, 0, 64 * sizeof(float), stream);
    pack_w_kernel<<<(NLAYER * TWOH * TWOH) / 256, 256, 0, stream>>>(Ws, Wi, Wt, Wf);
    pack_b_kernel<<<(NLAYER * TWOH) / 256, 256, 0, stream>>>(bs, bi, bt, bp);

    persistent_kernel<<<256, 512, 0, stream>>>(x, Wf, bp, deltas, out);
    result_kernel<<<1, 64, 0, stream>>>(deltas, out);
}

// Round 7
// 1257.299 us; speedup vs baseline: 4.5662x; 1.8908x over previous
//
#include <hip/hip_runtime.h>
#include <math.h>

#define HID 256
#define TWOH 512
#define ROWS 8192   // B*S
#define NLAYER 4
#define TMAX 50
#define DT 0.05f
#define EPSC 1e-3f

typedef float f32x4 __attribute__((ext_vector_type(4)));
typedef long  long2v __attribute__((ext_vector_type(2)));
typedef unsigned char u8;

// fp8 helpers (OCP e4m3 on gfx950)
__device__ inline u8 f32_to_fp8(float v) {
    return (u8)(__builtin_amdgcn_cvt_pk_fp8_f32(v, v, 0, 0) & 0xff);
}
__device__ inline float fp8_to_f32(u8 b) {
    return __builtin_amdgcn_cvt_f32_fp8((int)b, 0);
}

// ---------------------------------------------------------------------------
// Pair-packed fragment-major fp8 weights. Per wave-column-group wv
// (d-range [wv*32, wv*32+32)), fragment-PAIR (L,wv,ci,g) is 1024 B:
// lane's 16 B at lane*16 = { h=0 fragment 8 B | h=1 fragment 8 B } so the
// K-loop loads one dwordx4 per (ci,g) instead of two dwordx2.
//   g=0 -> tau columns, g=1 -> forcing columns; col d = wv*32 + h*16 + l15
//   k = ci*32 + quad*8 + j
// e bits: j:0-2, h:3, lane:4-9, g:10, ci:11-14, wv:15-17, L:18-19.
// tau row d: Wt[d][k]; forcing row d: k<256 ? Wi[d][k] : Ws[d][k-256].
// ---------------------------------------------------------------------------
__global__ void pack_w_kernel(const float* __restrict__ Ws,
                              const float* __restrict__ Wi,
                              const float* __restrict__ Wt,
                              u8* __restrict__ Wf) {
    int e = blockIdx.x * 256 + threadIdx.x;     // [0, 2^20)
    int j    = e & 7;
    int h    = (e >> 3) & 1;
    int lane = (e >> 4) & 63;
    int g    = (e >> 10) & 1;
    int ci   = (e >> 11) & 15;
    int wv   = (e >> 15) & 7;
    int L    = (e >> 18);
    int l15  = lane & 15;
    int quad = lane >> 4;
    int d = wv * 32 + h * 16 + l15;
    int k = ci * 32 + quad * 8 + j;
    float v;
    if (g == 0) {
        v = Wt[(size_t)L * HID * TWOH + (size_t)d * TWOH + k];
    } else {
        v = (k < HID) ? Wi[(size_t)L * HID * HID + (size_t)d * HID + k]
                      : Ws[(size_t)L * HID * HID + (size_t)d * HID + (k - HID)];
    }
    Wf[e] = f32_to_fp8(v);
}

__global__ void pack_b_kernel(const float* __restrict__ bs,
                              const float* __restrict__ bi,
                              const float* __restrict__ bt,
                              float* __restrict__ bp) {
    int idx = blockIdx.x * 256 + threadIdx.x;   // [0, 4*512): L*512 + n
    int L = idx / TWOH;
    int n = idx % TWOH;
    int d = n >> 1;
    bp[idx] = ((n & 1) == 0) ? bt[L * HID + d]
                             : (bs[L * HID + d] + bi[L * HID + d]);
}

// ---------------------------------------------------------------------------
// Persistent kernel: 256 blocks x 512 threads (8 waves, one col-group each;
// every wave computes both 16-row tiles mt=0,1). Block owns rows [32b,32b+32).
//
// Barrier structure (R6, kept): h double-buffered in LDS; per (t,L) stage =
//   upper-K (ci 8..15, A=h_prev, rs buffer) | barrier | lower-K (ci 0..7,
//   A=cur_in, ws side) | epilogue -- NO end-of-stage barrier (200 total).
//
// NEW vs R6: "#pragma unroll 1" on the L loop. R6 unrolled all 4 stages and
// the scheduler hoisted next-stage prefetches/A-reads across the epilogue
// (no barrier stops it) -> live ranges spanning stages -> spill at the
// 128-VGPR clamp -> 5.4 GB/launch scratch-reload traffic (FETCH 5.39e6 KB,
// 205 B/thread/stage). unroll 1 confines live ranges to one stage (~100
// regs, R0-proven scale); wave skew across the epilogue still happens at
// RUNTIME. Weights stream L2->registers as 1 KB pair-fragments, depth-4
// prefetch (32 VGPRs, same budget as R0's proven depth-4).
// ---------------------------------------------------------------------------
__global__ __launch_bounds__(512, 1) void persistent_kernel(
    const float* __restrict__ x,
    const u8* __restrict__ Wf,
    const float* __restrict__ bp,
    float* __restrict__ deltas,
    float* __restrict__ out)
{
    __shared__ u8 sX[32 * 256];                 //  8 KB
    __shared__ u8 sH[2][NLAYER][32 * 256];      // 64 KB (double-buffered)
    __shared__ float2 sBias[NLAYER][256];       //  8 KB (b_tau, b_forcing)

    const int tid  = threadIdx.x;
    const int lane = tid & 63;
    const int wv   = tid >> 6;               // 0..7 col group (d-base wv*32)
    const int l15  = lane & 15;
    const int quad = lane >> 4;              // 0..3
    const int w32  = wv * 32;
    const size_t rowbase = (size_t)blockIdx.x * 32;

    // ---- stage x -> sX (fp8, swizzled): 32 rows x 32 segs = 1024 units ----
    #pragma unroll
    for (int it = 0; it < 2; ++it) {
        int s = tid + it * 512;
        int r = s >> 5, seg = s & 31;
        const float* gx = x + (rowbase + r) * HID + seg * 8;
        float4 v0 = *(const float4*)gx;
        float4 v1 = *(const float4*)(gx + 4);
        int lo = __builtin_amdgcn_cvt_pk_fp8_f32(v0.x, v0.y, 0, 0);
        lo     = __builtin_amdgcn_cvt_pk_fp8_f32(v0.z, v0.w, lo, 1);
        int hi = __builtin_amdgcn_cvt_pk_fp8_f32(v1.x, v1.y, 0, 0);
        hi     = __builtin_amdgcn_cvt_pk_fp8_f32(v1.z, v1.w, hi, 1);
        long pk = ((long)(unsigned int)lo) | ((long)hi << 32);
        *(long*)&sX[r * 256 + (seg ^ r) * 8] = pk;
    }
    // ---- zero both h buffers: 64 KB = 8192 longs ----
    {
        long* hflat = (long*)&sH[0][0][0];
        #pragma unroll
        for (int it = 0; it < 16; ++it) hflat[tid + it * 512] = 0;
    }
    // ---- bias table -> LDS: 1024 entries ----
    #pragma unroll
    for (int it = 0; it < 2; ++it) {
        int i = tid + it * 512;
        sBias[i >> 8][i & 255] = *(const float2*)(bp + (i >> 8) * TWOH + 2 * (i & 255));
    }

    __syncthreads();

    #pragma unroll 1
    for (int t = 0; t < TMAX; ++t) {
        const int rs = t & 1, ws = rs ^ 1;
        #pragma unroll 1
        for (int L = 0; L < NLAYER; ++L) {
            const u8* Ahi = &sH[rs][L][0];                      // h_prev (k>=256)
            const u8* Alo = (L == 0) ? sX : &sH[ws][L - 1][0];  // cur_in (k<256)
            u8*       Hout = &sH[ws][L][0];
            // wave's pair-fragment stream: 32 KB contiguous per (L, wv)
            const u8* wb = Wf + ((size_t)(L * 8 + wv) << 15) + (size_t)lane * 16;

            f32x4 acc[2][4];   // [mt][0:tau ntp0, 1:tau ntp1, 2:forc ntp0, 3:forc ntp1]
            #pragma unroll
            for (int mt = 0; mt < 2; ++mt)
                #pragma unroll
                for (int n = 0; n < 4; ++n)
                    acc[mt][n] = (f32x4){0.f, 0.f, 0.f, 0.f};

            // K-step order: ci = 8..15 (h_prev half, pre-barrier), then 0..7.
            // depth-4 register prefetch of B pair-fragments (1 KB each).
            long2v bb[4][2];
            #pragma unroll
            for (int pi = 0; pi < 4; ++pi)
                #pragma unroll
                for (int g = 0; g < 2; ++g)
                    bb[pi][g] = *(const long2v*)(wb + (size_t)(((8 + pi) * 2 + g) << 10));

            #pragma unroll
            for (int s = 0; s < 16; ++s) {
                const int ci = (s < 8) ? (s + 8) : (s - 8);
                const int p = s & 3;
                if (s == 8) __syncthreads();   // sH[ws][L-1] now published
                const u8* Asrc = (s < 8) ? Ahi : Alo;   // static under unroll
                const int seg = (ci & 7) * 4 + quad;    // 8-B seg in [0,32)
                long a[2];
                #pragma unroll
                for (int mt = 0; mt < 2; ++mt) {
                    const int row = mt * 16 + l15;
                    a[mt] = *(const long*)&Asrc[row * 256 + (seg ^ row) * 8];
                }
                #pragma unroll
                for (int mt = 0; mt < 2; ++mt)
                    #pragma unroll
                    for (int n = 0; n < 4; ++n)
                        acc[mt][n] = __builtin_amdgcn_mfma_f32_16x16x32_fp8_fp8(
                            a[mt], bb[p][n >> 1][n & 1], acc[mt][n], 0, 0, 0);
                if (s + 4 < 16) {
                    const int nci = (s + 4 < 8) ? (s + 12) : (s - 4);
                    #pragma unroll
                    for (int g = 0; g < 2; ++g)
                        bb[p][g] = *(const long2v*)(wb + (size_t)((nci * 2 + g) << 10));
                }
            }

            // Epilogue. C/D: col = l15 (tile ntp), row = mt*16 + quad*4 + r.
            // Old h read from rs buffer; new h written to ws buffer. No
            // barrier after (next stage's mid-barrier protects readers).
            float dmax = 0.0f;
            #pragma unroll
            for (int ntp = 0; ntp < 2; ++ntp) {
                const int d = w32 + ntp * 16 + l15;
                const float2 b2 = sBias[L][d];
                const int seg = d >> 3, dlow = d & 7;
                #pragma unroll
                for (int mt = 0; mt < 2; ++mt) {
                    #pragma unroll
                    for (int r = 0; r < 4; ++r) {
                        float tpre = acc[mt][ntp][r]     + b2.x;
                        float fpre = acc[mt][ntp + 2][r] + b2.y;
                        tpre = fminf(30.f, fmaxf(-30.f, tpre));
                        fpre = fminf(15.f, fmaxf(-15.f, fpre));
                        // h/(sigma(t)+1e-6) == h*(1+u)/(1+eps+eps*u), u=e^-t
                        float u   = __expf(-tpre);
                        float den = 1.0f + 1e-6f + 1e-6f * u;
                        float rcp = __builtin_amdgcn_rcpf(den);
                        float e2  = __expf(2.0f * fpre);
                        float r2  = __builtin_amdgcn_rcpf(e2 + 1.0f);
                        float fo  = (e2 - 1.0f) * r2;
                        const int row = mt * 16 + quad * 4 + r;
                        const int idx = row * 256 + (seg ^ row) * 8 + dlow;
                        float h  = fp8_to_f32(Ahi[idx]);
                        float gq = h * (1.0f + u) * rcp;
                        float nv = h + DT * (fo - gq);
                        nv = fminf(10.0f, fmaxf(-10.0f, nv));
                        Hout[idx] = f32_to_fp8(nv);
                        dmax = fmaxf(dmax, fabsf(nv - h));
                    }
                }
            }
            if (L == NLAYER - 1) {
                #pragma unroll
                for (int off = 32; off > 0; off >>= 1)
                    dmax = fmaxf(dmax, __shfl_xor(dmax, off));
                if (lane == 0)
                    atomicMax((unsigned int*)(deltas + t), __float_as_uint(dmax));
            }
        } // L
    } // t

    __syncthreads();   // all epilogue writes of t=TMAX-1 visible

    // ---- final output: layer-3 states from write-side of t=TMAX-1 ----
    {
        const u8* fin = &sH[((TMAX - 1) & 1) ^ 1][NLAYER - 1][0];
        #pragma unroll
        for (int it = 0; it < 2; ++it) {
            int s = tid + it * 512;
            int r = s >> 5, seg = s & 31;
            long v = *(const long*)&fin[r * 256 + (seg ^ r) * 8];
            int lo = (int)(v & 0xffffffffl);
            int hi = (int)(v >> 32);
            float* go = out + (rowbase + r) * HID + seg * 8;
            float4 o0, o1;
            o0.x = __builtin_amdgcn_cvt_f32_fp8(lo, 0);
            o0.y = __builtin_amdgcn_cvt_f32_fp8(lo, 1);
            o0.z = __builtin_amdgcn_cvt_f32_fp8(lo, 2);
            o0.w = __builtin_amdgcn_cvt_f32_fp8(lo, 3);
            o1.x = __builtin_amdgcn_cvt_f32_fp8(hi, 0);
            o1.y = __builtin_amdgcn_cvt_f32_fp8(hi, 1);
            o1.z = __builtin_amdgcn_cvt_f32_fp8(hi, 2);
            o1.w = __builtin_amdgcn_cvt_f32_fp8(hi, 3);
            *(float4*)go = o0;
            *(float4*)(go + 4) = o1;
        }
    }
}

__global__ void result_kernel(const float* __restrict__ deltas,
                              float* __restrict__ out) {
    if (threadIdx.x == 0) {
        int res = TMAX;
        for (int t = 0; t < TMAX; ++t) {
            if (deltas[t] < EPSC) { res = t; break; }
        }
        out[(size_t)ROWS * HID] = (float)res;
    }
}

// ---------------------------------------------------------------------------
extern "C" void kernel_launch(void* const* d_in, const int* in_sizes, int n_in,
                              void* d_out, int out_size, void* d_ws, size_t ws_size,
                              hipStream_t stream) {
    const float* x  = (const float*)d_in[0];
    const float* Ws = (const float*)d_in[1];
    const float* bs = (const float*)d_in[2];
    const float* Wi = (const float*)d_in[3];
    const float* bi = (const float*)d_in[4];
    const float* Wt = (const float*)d_in[5];
    const float* bt = (const float*)d_in[6];
    float* out = (float*)d_out;

    char* p = (char*)d_ws;
    u8*    Wf     = (u8*)p;    p += (size_t)NLAYER * TWOH * TWOH;            // 1 MB
    float* bp     = (float*)p; p += (size_t)NLAYER * TWOH * sizeof(float);   // 8 KB
    float* deltas = (float*)p; p += 64 * sizeof(float);

    hipMemsetAsync(deltas, 0, 64 * sizeof(float), stream);
    pack_w_kernel<<<(NLAYER * TWOH * TWOH) / 256, 256, 0, stream>>>(Ws, Wi, Wt, Wf);
    pack_b_kernel<<<(NLAYER * TWOH) / 256, 256, 0, stream>>>(bs, bi, bt, bp);

    persistent_kernel<<<256, 512, 0, stream>>>(x, Wf, bp, deltas, out);
    result_kernel<<<1, 64, 0, stream>>>(deltas, out);
}